// Round 9
// baseline (494.432 us; speedup 1.0000x reference)
//
#include <hip/hip_runtime.h>
#include <hip/hip_fp16.h>
#include <hip/hip_cooperative_groups.h>

namespace cg = cooperative_groups;

// ---------------------------------------------------------------------------
// VGAE encoder, gather-form, fp16 gather table.
//   a[i] = dis_i*(g[i] + sum_{e:dst=i} g[src_e]),  g = fp16(dis (.) h)
// R12: agg+GEMM fused per 64-node block via LDS epilogue (294 -> 249 us).
// R13 FAILED: coop mega-kernel 517 us — but confounded: atomic dispenser +
//   __launch_bounds__(256,4) cap + grid=1024 persistence.
// R14 FAILED: degree-sort perm (+33, scattered locality).
// R15 FAILED: 8x-split finalize (+7, duplicated histograms).
// R17: 16-deep gather ILP (244.8 us, BEST). R18 FAILED (+106, atomic scatter
//   thrashed L2). R19 FAILED (+28, partials stream evicted the L2 slice).
// FLOOR ARITHMETIC (R20): gather traffic is compulsory — 1.6M edges x 64 B
//   full-line = 102 MB/layer ~= 97 MB measured; 2.5 TB/s random-line rate
//   invariant under ILP/sort/phase/structure. Layers are at their floor.
// R20: CLEAN coop retry to remove 2 dispatch boundaries: static tile =
//   blockIdx (no dispenser), no launch-bounds cap, grid = min(queried
//   capacity, ntiles) with tile-stride fallback, threadfence+grid.sync
//   between layers. Everything else R17-exact.
//   NT loads ONLY on read-once streams (src/dst). NT stores banned (R10).
// ---------------------------------------------------------------------------

#define BK_BITS 9
#define BK      (1 << BK_BITS)     // 512 dst nodes per bucket
#define BMASK   (BK - 1)
#define EPT     16
#define CHUNK   (256 * EPT)        // 4096 edges per block
#define CAP     16384              // bucket capacity (mean 8192, max ~8.6k)

typedef int   vint4   __attribute__((ext_vector_type(4)));
typedef uint  vuint4  __attribute__((ext_vector_type(4)));
typedef float vfloat4 __attribute__((ext_vector_type(4)));

#define NTL(p) __builtin_nontemporal_load(p)

// ---- pass A: scatter edges into capacity-padded dst-buckets ----------------
__global__ void k_bucket(const int* __restrict__ src, const int* __restrict__ dst,
                         int* __restrict__ bcur, int* __restrict__ ebuf, int E) {
    __shared__ int lcnt[256];
    __shared__ int lbase[256];
    int t = threadIdx.x;
    lcnt[t] = 0;
    __syncthreads();
    int e0 = blockIdx.x * CHUNK;
    int pk[EPT];
#pragma unroll
    for (int i = 0; i < EPT; ++i) {
        int e = e0 + i * 256 + t;
        pk[i] = -1;
        if (e < E) {
            int d = NTL(dst + e);
            int b = d >> BK_BITS;
            int off = atomicAdd(&lcnt[b], 1);          // off < CHUNK = 4096
            pk[i] = (b << 21) | (off << BK_BITS) | (d & BMASK);
        }
    }
    __syncthreads();
    lbase[t] = t * CAP + atomicAdd(&bcur[t], lcnt[t]);
    __syncthreads();
#pragma unroll
    for (int i = 0; i < EPT; ++i) {
        int e = e0 + i * 256 + t;
        if (e < E) {
            int b   = pk[i] >> 21;
            int off = (pk[i] >> BK_BITS) & 4095;
            int dl  = pk[i] & BMASK;
            int pos = lbase[b] + off;
            if (pos < (b + 1) * CAP)                  // overflow guard (never hit)
                ebuf[pos] = (NTL(src + e) << BK_BITS) | dl;
        }
    }
}

// ---- pass B: per-bucket finalize: starts, dis, sorted src, g0 --------------
__global__ void k_finalize(const int* __restrict__ bcur, int* __restrict__ starts,
                           float* __restrict__ dis, const int* __restrict__ ebuf,
                           int* __restrict__ es, const float* __restrict__ x,
                           __half* __restrict__ g0, int n, int E) {
    __shared__ int   hist[BK];
    __shared__ int   sc[BK];
    __shared__ int   sb[256];
    __shared__ float disL[BK];
    int b = blockIdx.x, t = threadIdx.x;
    if (t < 256) sb[t] = min(bcur[t], CAP);
    hist[t] = 0;
    __syncthreads();
    for (int o = 1; o < 256; o <<= 1) {
        int xv = 0;
        if (t < 256 && t >= o) xv = sb[t - o];
        __syncthreads();
        if (t < 256) sb[t] += xv;
        __syncthreads();
    }
    int cnt = min(bcur[b], CAP);
    int beg = sb[b] - cnt;                  // exclusive scan at b
    const int* eb = ebuf + (size_t)b * CAP;
    for (int j = t; j < cnt; j += BK)
        atomicAdd(&hist[eb[j] & BMASK], 1);
    __syncthreads();
    int cv = hist[t];
    sc[t] = cv;
    __syncthreads();
    for (int o = 1; o < BK; o <<= 1) {
        int xv = (t >= o) ? sc[t - o] : 0;
        __syncthreads();
        sc[t] += xv;
        __syncthreads();
    }
    int excl = sc[t] - cv;
    int gnode = (b << BK_BITS) + t;
    float dv = rsqrtf((float)cv + 1.0f);    // +1 = self loop
    disL[t] = dv;
    if (gnode < n) {
        starts[gnode] = beg + excl;
        dis[gnode] = dv;
    }
    if (b == 0 && t == 0) starts[n] = E;
    hist[t] = excl;                         // reuse as cursor
    __syncthreads();
    for (int j = t; j < cnt; j += BK) {
        int v = eb[j];
        int off = atomicAdd(&hist[v & BMASK], 1);
        es[beg + off] = v >> BK_BITS;       // normal store: L2 combines
    }
    // g0 = fp16(dis (.) x) for this bucket's nodes (coalesced 8 B stores)
    int node0 = b << BK_BITS;
    const float4* x4 = (const float4*)x;
    uint2* g2 = (uint2*)g0;
    for (int idx = t; idx < BK * 8; idx += BK) {
        int r = idx >> 3, lane = idx & 7;
        int nd = node0 + r;
        if (nd < n) {
            float d = disL[r];
            float4 v = x4[(size_t)nd * 8 + lane];
            __half2 lo = __floats2half2_rn(d * v.x, d * v.y);
            __half2 hi = __floats2half2_rn(d * v.z, d * v.w);
            uint2 u;
            u.x = *(unsigned int*)&lo;
            u.y = *(unsigned int*)&hi;
            g2[(size_t)nd * 8 + lane] = u;
        }
    }
}

// ---- gather helper: accumulate 8 halves into fp32 --------------------------
__device__ inline void acc8(uint4 u, float* s) {
    __half2 h0 = *(__half2*)&u.x, h1 = *(__half2*)&u.y;
    __half2 h2 = *(__half2*)&u.z, h3 = *(__half2*)&u.w;
    float2 f0 = __half22float2(h0), f1 = __half22float2(h1);
    float2 f2 = __half22float2(h2), f3 = __half22float2(h3);
    s[0] += f0.x; s[1] += f0.y; s[2] += f1.x; s[3] += f1.y;
    s[4] += f2.x; s[5] += f2.y; s[6] += f3.x; s[7] += f3.y;
}

// ---- gather core: s[8] = self + sum over edge list (fp32 accum) ------------
// 16 gathers in flight (R17).
__device__ inline void gather32(const int* __restrict__ starts,
                                const int* __restrict__ es,
                                const uint4* __restrict__ g4,
                                int node, int lane, float* s) {
    acc8(g4[(size_t)node * 4 + lane], s);  // self term
    int j = starts[node], end = starts[node + 1];
    while (j < end && (j & 3)) {           // align to int4 boundary
        acc8(g4[(size_t)es[j] * 4 + lane], s);
        ++j;
    }
    for (; j + 16 <= end; j += 16) {       // 16 gathers in flight
        int4 e0 = *(const int4*)(es + j);
        int4 e1 = *(const int4*)(es + j + 4);
        int4 e2 = *(const int4*)(es + j + 8);
        int4 e3 = *(const int4*)(es + j + 12);
        uint4 u0  = g4[(size_t)e0.x * 4 + lane];
        uint4 u1  = g4[(size_t)e0.y * 4 + lane];
        uint4 u2  = g4[(size_t)e0.z * 4 + lane];
        uint4 u3  = g4[(size_t)e0.w * 4 + lane];
        uint4 u4  = g4[(size_t)e1.x * 4 + lane];
        uint4 u5  = g4[(size_t)e1.y * 4 + lane];
        uint4 u6  = g4[(size_t)e1.z * 4 + lane];
        uint4 u7  = g4[(size_t)e1.w * 4 + lane];
        uint4 u8  = g4[(size_t)e2.x * 4 + lane];
        uint4 u9  = g4[(size_t)e2.y * 4 + lane];
        uint4 u10 = g4[(size_t)e2.z * 4 + lane];
        uint4 u11 = g4[(size_t)e2.w * 4 + lane];
        uint4 u12 = g4[(size_t)e3.x * 4 + lane];
        uint4 u13 = g4[(size_t)e3.y * 4 + lane];
        uint4 u14 = g4[(size_t)e3.z * 4 + lane];
        uint4 u15 = g4[(size_t)e3.w * 4 + lane];
        acc8(u0, s);  acc8(u1, s);  acc8(u2, s);  acc8(u3, s);
        acc8(u4, s);  acc8(u5, s);  acc8(u6, s);  acc8(u7, s);
        acc8(u8, s);  acc8(u9, s);  acc8(u10, s); acc8(u11, s);
        acc8(u12, s); acc8(u13, s); acc8(u14, s); acc8(u15, s);
    }
    if (j + 8 <= end) {
        int4 e0 = *(const int4*)(es + j);
        int4 e1 = *(const int4*)(es + j + 4);
        uint4 u0 = g4[(size_t)e0.x * 4 + lane];
        uint4 u1 = g4[(size_t)e0.y * 4 + lane];
        uint4 u2 = g4[(size_t)e0.z * 4 + lane];
        uint4 u3 = g4[(size_t)e0.w * 4 + lane];
        uint4 u4 = g4[(size_t)e1.x * 4 + lane];
        uint4 u5 = g4[(size_t)e1.y * 4 + lane];
        uint4 u6 = g4[(size_t)e1.z * 4 + lane];
        uint4 u7 = g4[(size_t)e1.w * 4 + lane];
        acc8(u0, s); acc8(u1, s); acc8(u2, s); acc8(u3, s);
        acc8(u4, s); acc8(u5, s); acc8(u6, s); acc8(u7, s);
        j += 8;
    }
    if (j + 4 <= end) {
        int4 e0 = *(const int4*)(es + j);
        uint4 u0 = g4[(size_t)e0.x * 4 + lane];
        uint4 u1 = g4[(size_t)e0.y * 4 + lane];
        uint4 u2 = g4[(size_t)e0.z * 4 + lane];
        uint4 u3 = g4[(size_t)e0.w * 4 + lane];
        acc8(u0, s); acc8(u1, s); acc8(u2, s); acc8(u3, s);
        j += 4;
    }
    for (; j < end; ++j) acc8(g4[(size_t)es[j] * 4 + lane], s);
}

// ---- hidden-layer phase (static tiles, stride = gridDim) -------------------
__device__ __forceinline__ void hidden_phase(
        const int* __restrict__ starts, const int* __restrict__ es,
        const float* __restrict__ dis, const __half* __restrict__ g,
        const float* __restrict__ W, const float* __restrict__ bias,
        __half* __restrict__ gout, int n, int ntiles,
        float* __restrict__ WsB, float (* __restrict__ Xs)[33]) {
    int t = threadIdx.x;
    for (int i = t; i < 1024; i += 256) WsB[(i >> 5) * 33 + (i & 31)] = W[i];
    int r = t >> 2, lane = t & 3, c0 = lane * 8;
    for (int tile = blockIdx.x; tile < ntiles; tile += gridDim.x) {
        int node = tile * 64 + r;
        bool alive = node < n;
        float dd = 0.f;
        if (alive) {
            float s[8] = {0, 0, 0, 0, 0, 0, 0, 0};
            gather32(starts, es, (const uint4*)g, node, lane, s);
            dd = dis[node];
#pragma unroll
            for (int i = 0; i < 8; ++i) Xs[r][c0 + i] = dd * s[i];
        }
        __syncthreads();                   // Ws + Xs visible
        if (alive) {
            float acc[8];
#pragma unroll
            for (int i = 0; i < 8; ++i) acc[i] = bias[c0 + i];
#pragma unroll 8
            for (int k = 0; k < 32; ++k) {
                float xv = Xs[r][k];
#pragma unroll
                for (int i = 0; i < 8; ++i) acc[i] += xv * WsB[k * 33 + c0 + i];
            }
            __half2 h0 = __floats2half2_rn(dd * fmaxf(acc[0], 0.f), dd * fmaxf(acc[1], 0.f));
            __half2 h1 = __floats2half2_rn(dd * fmaxf(acc[2], 0.f), dd * fmaxf(acc[3], 0.f));
            __half2 h2 = __floats2half2_rn(dd * fmaxf(acc[4], 0.f), dd * fmaxf(acc[5], 0.f));
            __half2 h3 = __floats2half2_rn(dd * fmaxf(acc[6], 0.f), dd * fmaxf(acc[7], 0.f));
            uint4 u;
            u.x = *(unsigned int*)&h0; u.y = *(unsigned int*)&h1;
            u.z = *(unsigned int*)&h2; u.w = *(unsigned int*)&h3;
            ((uint4*)gout)[(size_t)node * 4 + lane] = u;
        }
        __syncthreads();                   // Xs reuse safe next tile
    }
}

// ---- output phase ----------------------------------------------------------
__device__ __forceinline__ void final_phase(
        const int* __restrict__ starts, const int* __restrict__ es,
        const float* __restrict__ dis, const __half* __restrict__ g,
        const float* __restrict__ Wmu, const float* __restrict__ Wlv,
        const float* __restrict__ bmu, const float* __restrict__ blv,
        float* __restrict__ out, int n, int ntiles,
        float* __restrict__ WsB, float (* __restrict__ Xs)[33]) {
    int t = threadIdx.x;
    for (int i = t; i < 1024; i += 256) {
        WsB[(i >> 5) * 66 + (i & 31)]      = Wmu[i];
        WsB[(i >> 5) * 66 + 32 + (i & 31)] = Wlv[i];
    }
    int r = t >> 2, lane = t & 3, c0 = lane * 8;
    for (int tile = blockIdx.x; tile < ntiles; tile += gridDim.x) {
        int node = tile * 64 + r;
        bool alive = node < n;
        if (alive) {
            float s[8] = {0, 0, 0, 0, 0, 0, 0, 0};
            gather32(starts, es, (const uint4*)g, node, lane, s);
            float dd = dis[node];
#pragma unroll
            for (int i = 0; i < 8; ++i) Xs[r][c0 + i] = dd * s[i];
        }
        __syncthreads();
        if (alive) {
            float am[8], al[8];
#pragma unroll
            for (int i = 0; i < 8; ++i) { am[i] = bmu[c0 + i]; al[i] = blv[c0 + i]; }
#pragma unroll 4
            for (int k = 0; k < 32; ++k) {
                float xv = Xs[r][k];
#pragma unroll
                for (int i = 0; i < 8; ++i) {
                    am[i] += xv * WsB[k * 66 + c0 + i];
                    al[i] += xv * WsB[k * 66 + 32 + c0 + i];
                }
            }
            float4* om = (float4*)out + (size_t)node * 8 + lane * 2;
            om[0] = make_float4(am[0], am[1], am[2], am[3]);
            om[1] = make_float4(am[4], am[5], am[6], am[7]);
            float4* ol = (float4*)(out + (size_t)n * 32) + (size_t)node * 8 + lane * 2;
            ol[0] = make_float4(al[0], al[1], al[2], al[3]);
            ol[1] = make_float4(al[4], al[5], al[6], al[7]);
        }
        __syncthreads();
    }
}

// ---- cooperative 3-layer kernel (static tiles, no dispenser) ---------------
__global__ void k_layers3(const int* starts, const int* es, const float* dis,
                          __half* gA, __half* gB,
                          const float* W1, const float* b1,
                          const float* W2, const float* b2,
                          const float* Wmu, const float* Wlv,
                          const float* bmu, const float* blv,
                          float* out, int n, int ntiles) {
    __shared__ float WsB[32 * 66];
    __shared__ float Xs[64][33];
    cg::grid_group grid = cg::this_grid();
    hidden_phase(starts, es, dis, gA, W1, b1, gB, n, ntiles, WsB, Xs);
    __threadfence();
    grid.sync();
    hidden_phase(starts, es, dis, gB, W2, b2, gA, n, ntiles, WsB, Xs);
    __threadfence();
    grid.sync();
    final_phase(starts, es, dis, gA, Wmu, Wlv, bmu, blv, out, n, ntiles, WsB, Xs);
}

// ---- launch ----------------------------------------------------------------

extern "C" void kernel_launch(void* const* d_in, const int* in_sizes, int n_in,
                              void* d_out, int out_size, void* d_ws, size_t ws_size,
                              hipStream_t stream) {
    const float* x   = (const float*)d_in[0];
    const int*   ei  = (const int*)d_in[1];
    const float* W1  = (const float*)d_in[2];
    const float* b1  = (const float*)d_in[3];
    const float* W2  = (const float*)d_in[4];
    const float* b2  = (const float*)d_in[5];
    const float* Wmu = (const float*)d_in[6];
    const float* bmu = (const float*)d_in[7];
    const float* Wlv = (const float*)d_in[8];
    const float* blv = (const float*)d_in[9];
    float* out = (float*)d_out;

    int n = in_sizes[0] / 32;   // 100000
    int E = in_sizes[1] / 2;    // 1600000
    const int* src = ei;
    const int* dst = ei + E;
    int nbuck = (n + BK - 1) >> BK_BITS;   // 196 (<= 256)

    // workspace layout (all segments 16B-aligned)
    int*    bcur   = (int*)d_ws;                      // 256
    int     npad   = (n + 4) & ~3;
    int*    starts = bcur + 256;                      // n+1 (padded)
    float*  dis    = (float*)(starts + npad);         // n
    int*    es     = (int*)(dis + n);                 // E
    __half* gA     = (__half*)(es + E);               // n*32 fp16
    __half* gB     = gA + (size_t)n * 32;             // n*32 fp16
    int*    ebuf   = (int*)(gB + (size_t)n * 32);     // 256*CAP ints (16.8 MB)

    int nblk   = (E + CHUNK - 1) / CHUNK;  // 391
    int ntiles = (n + 63) / 64;            // 1563

    // ---- edge preprocessing ----
    hipMemsetAsync(bcur, 0, 256 * sizeof(int), stream);
    k_bucket<<<nblk, 256, 0, stream>>>(src, dst, bcur, ebuf, E);
    k_finalize<<<nbuck, BK, 0, stream>>>(bcur, starts, dis, ebuf, es, x, gA, n, E);

    // ---- all three layers, one cooperative kernel, static tiles ----
    static int coopCap = 0;
    if (coopCap == 0) {
        int mb = 0;
        if (hipOccupancyMaxActiveBlocksPerMultiprocessor(&mb, k_layers3, 256, 0) != hipSuccess || mb < 1)
            mb = 4;
        coopCap = mb * 256;                // 256 CUs
    }
    int cgrid = coopCap < ntiles ? coopCap : ntiles;
    void* kargs[] = {(void*)&starts, (void*)&es, (void*)&dis, (void*)&gA, (void*)&gB,
                     (void*)&W1, (void*)&b1, (void*)&W2, (void*)&b2,
                     (void*)&Wmu, (void*)&Wlv, (void*)&bmu, (void*)&blv,
                     (void*)&out, (void*)&n, (void*)&ntiles};
    hipLaunchCooperativeKernel(k_layers3, dim3(cgrid), dim3(256), kargs, 0, stream);
}

// Round 10
// 243.305 us; speedup vs baseline: 2.0321x; 2.0321x over previous
//
#include <hip/hip_runtime.h>
#include <hip/hip_fp16.h>

// ---------------------------------------------------------------------------
// VGAE encoder, gather-form, fp16 gather table.  FINAL (R21 = R17 restore).
//   a[i] = dis_i*(g[i] + sum_{e:dst=i} g[src_e]),  g = fp16(dis (.) h)
// Ledger:
// R12: agg+GEMM fused per 64-node block via LDS epilogue (294 -> 249 us) WIN
// R13/R20 FAILED: coop mega-kernel (517/494 us). Even with static tiles, no
//   dispenser, full grid: coop launch itself degrades the random-gather path
//   5x (519 vs 2470 GB/s at same pattern+occupancy). Coop is dead here.
// R14 FAILED: degree-sort perm (+33, scattered locality).
// R15 FAILED: 8x-split finalize (+7, duplicated histograms).
// R17: 16 outstanding gathers/wave (-4.4 -> 244.8 us, BEST).
// R18 FAILED: flat global-atomic preproc (+106, L2 writeback thrash).
// R19 FAILED: src-phase L2 split (+28, partial round-trip >= L2 gain).
// ROOFLINE ARGUMENT: gather traffic is compulsory (1.6M edges x 64 B
//   full-line = 102 MB/layer ~= 97 MB measured FETCH; ~0 L2 hit since the
//   6.4 MB table > 4 MB per-XCD L2, uniform-random src). Rate 2.4-2.5 TB/s
//   invariant across 7 structural variants. Budget: 44 us harness fill +
//   ~15-20 preproc + ~135-140 gather layers + ~15 boundaries ~= 215-225;
//   measured 244.8. No pipe counter (VALU 14%, MFMA 0, HBM 31%) near peak;
//   binding resource is the L2-miss/fill path on random 64 B lines.
//   NT loads ONLY on read-once streams (src/dst). NT stores banned (R10).
// ---------------------------------------------------------------------------

#define BK_BITS 9
#define BK      (1 << BK_BITS)     // 512 dst nodes per bucket
#define BMASK   (BK - 1)
#define EPT     16
#define CHUNK   (256 * EPT)        // 4096 edges per block
#define CAP     16384              // bucket capacity (mean 8192, max ~8.6k)

typedef int   vint4   __attribute__((ext_vector_type(4)));
typedef uint  vuint4  __attribute__((ext_vector_type(4)));
typedef float vfloat4 __attribute__((ext_vector_type(4)));

#define NTL(p) __builtin_nontemporal_load(p)

// ---- pass A: scatter edges into capacity-padded dst-buckets ----------------
__global__ void k_bucket(const int* __restrict__ src, const int* __restrict__ dst,
                         int* __restrict__ bcur, int* __restrict__ ebuf, int E) {
    __shared__ int lcnt[256];
    __shared__ int lbase[256];
    int t = threadIdx.x;
    lcnt[t] = 0;
    __syncthreads();
    int e0 = blockIdx.x * CHUNK;
    int pk[EPT];
#pragma unroll
    for (int i = 0; i < EPT; ++i) {
        int e = e0 + i * 256 + t;
        pk[i] = -1;
        if (e < E) {
            int d = NTL(dst + e);
            int b = d >> BK_BITS;
            int off = atomicAdd(&lcnt[b], 1);          // off < CHUNK = 4096
            pk[i] = (b << 21) | (off << BK_BITS) | (d & BMASK);
        }
    }
    __syncthreads();
    lbase[t] = t * CAP + atomicAdd(&bcur[t], lcnt[t]);
    __syncthreads();
#pragma unroll
    for (int i = 0; i < EPT; ++i) {
        int e = e0 + i * 256 + t;
        if (e < E) {
            int b   = pk[i] >> 21;
            int off = (pk[i] >> BK_BITS) & 4095;
            int dl  = pk[i] & BMASK;
            int pos = lbase[b] + off;
            if (pos < (b + 1) * CAP)                  // overflow guard (never hit)
                ebuf[pos] = (NTL(src + e) << BK_BITS) | dl;
        }
    }
}

// ---- pass B: per-bucket finalize: starts, dis, sorted src, g0 --------------
__global__ void k_finalize(const int* __restrict__ bcur, int* __restrict__ starts,
                           float* __restrict__ dis, const int* __restrict__ ebuf,
                           int* __restrict__ es, const float* __restrict__ x,
                           __half* __restrict__ g0, int n, int E) {
    __shared__ int   hist[BK];
    __shared__ int   sc[BK];
    __shared__ int   sb[256];
    __shared__ float disL[BK];
    int b = blockIdx.x, t = threadIdx.x;
    if (t < 256) sb[t] = min(bcur[t], CAP);
    hist[t] = 0;
    __syncthreads();
    for (int o = 1; o < 256; o <<= 1) {
        int xv = 0;
        if (t < 256 && t >= o) xv = sb[t - o];
        __syncthreads();
        if (t < 256) sb[t] += xv;
        __syncthreads();
    }
    int cnt = min(bcur[b], CAP);
    int beg = sb[b] - cnt;                  // exclusive scan at b
    const int* eb = ebuf + (size_t)b * CAP;
    for (int j = t; j < cnt; j += BK)
        atomicAdd(&hist[eb[j] & BMASK], 1);
    __syncthreads();
    int cv = hist[t];
    sc[t] = cv;
    __syncthreads();
    for (int o = 1; o < BK; o <<= 1) {
        int xv = (t >= o) ? sc[t - o] : 0;
        __syncthreads();
        sc[t] += xv;
        __syncthreads();
    }
    int excl = sc[t] - cv;
    int gnode = (b << BK_BITS) + t;
    float dv = rsqrtf((float)cv + 1.0f);    // +1 = self loop
    disL[t] = dv;
    if (gnode < n) {
        starts[gnode] = beg + excl;
        dis[gnode] = dv;
    }
    if (b == 0 && t == 0) starts[n] = E;
    hist[t] = excl;                         // reuse as cursor
    __syncthreads();
    for (int j = t; j < cnt; j += BK) {
        int v = eb[j];
        int off = atomicAdd(&hist[v & BMASK], 1);
        es[beg + off] = v >> BK_BITS;       // normal store: L2 combines
    }
    // g0 = fp16(dis (.) x) for this bucket's nodes (coalesced 8 B stores)
    int node0 = b << BK_BITS;
    const float4* x4 = (const float4*)x;
    uint2* g2 = (uint2*)g0;
    for (int idx = t; idx < BK * 8; idx += BK) {
        int r = idx >> 3, lane = idx & 7;
        int nd = node0 + r;
        if (nd < n) {
            float d = disL[r];
            float4 v = x4[(size_t)nd * 8 + lane];
            __half2 lo = __floats2half2_rn(d * v.x, d * v.y);
            __half2 hi = __floats2half2_rn(d * v.z, d * v.w);
            uint2 u;
            u.x = *(unsigned int*)&lo;
            u.y = *(unsigned int*)&hi;
            g2[(size_t)nd * 8 + lane] = u;
        }
    }
}

// ---- gather helper: accumulate 8 halves into fp32 --------------------------
__device__ inline void acc8(uint4 u, float* s) {
    __half2 h0 = *(__half2*)&u.x, h1 = *(__half2*)&u.y;
    __half2 h2 = *(__half2*)&u.z, h3 = *(__half2*)&u.w;
    float2 f0 = __half22float2(h0), f1 = __half22float2(h1);
    float2 f2 = __half22float2(h2), f3 = __half22float2(h3);
    s[0] += f0.x; s[1] += f0.y; s[2] += f1.x; s[3] += f1.y;
    s[4] += f2.x; s[5] += f2.y; s[6] += f3.x; s[7] += f3.y;
}

// ---- gather core: s[8] = self + sum over edge list (fp32 accum) ------------
// 16 gathers in flight (R17): all loads issued before any accumulate; the
// compiler's counted vmcnt lets acc8(u0) start as soon as load 0 retires.
__device__ inline void gather32(const int* __restrict__ starts,
                                const int* __restrict__ es,
                                const uint4* __restrict__ g4,
                                int node, int lane, float* s) {
    acc8(g4[(size_t)node * 4 + lane], s);  // self term
    int j = starts[node], end = starts[node + 1];
    while (j < end && (j & 3)) {           // align to int4 boundary
        acc8(g4[(size_t)es[j] * 4 + lane], s);
        ++j;
    }
    for (; j + 16 <= end; j += 16) {       // 16 gathers in flight
        int4 e0 = *(const int4*)(es + j);
        int4 e1 = *(const int4*)(es + j + 4);
        int4 e2 = *(const int4*)(es + j + 8);
        int4 e3 = *(const int4*)(es + j + 12);
        uint4 u0  = g4[(size_t)e0.x * 4 + lane];
        uint4 u1  = g4[(size_t)e0.y * 4 + lane];
        uint4 u2  = g4[(size_t)e0.z * 4 + lane];
        uint4 u3  = g4[(size_t)e0.w * 4 + lane];
        uint4 u4  = g4[(size_t)e1.x * 4 + lane];
        uint4 u5  = g4[(size_t)e1.y * 4 + lane];
        uint4 u6  = g4[(size_t)e1.z * 4 + lane];
        uint4 u7  = g4[(size_t)e1.w * 4 + lane];
        uint4 u8  = g4[(size_t)e2.x * 4 + lane];
        uint4 u9  = g4[(size_t)e2.y * 4 + lane];
        uint4 u10 = g4[(size_t)e2.z * 4 + lane];
        uint4 u11 = g4[(size_t)e2.w * 4 + lane];
        uint4 u12 = g4[(size_t)e3.x * 4 + lane];
        uint4 u13 = g4[(size_t)e3.y * 4 + lane];
        uint4 u14 = g4[(size_t)e3.z * 4 + lane];
        uint4 u15 = g4[(size_t)e3.w * 4 + lane];
        acc8(u0, s);  acc8(u1, s);  acc8(u2, s);  acc8(u3, s);
        acc8(u4, s);  acc8(u5, s);  acc8(u6, s);  acc8(u7, s);
        acc8(u8, s);  acc8(u9, s);  acc8(u10, s); acc8(u11, s);
        acc8(u12, s); acc8(u13, s); acc8(u14, s); acc8(u15, s);
    }
    if (j + 8 <= end) {
        int4 e0 = *(const int4*)(es + j);
        int4 e1 = *(const int4*)(es + j + 4);
        uint4 u0 = g4[(size_t)e0.x * 4 + lane];
        uint4 u1 = g4[(size_t)e0.y * 4 + lane];
        uint4 u2 = g4[(size_t)e0.z * 4 + lane];
        uint4 u3 = g4[(size_t)e0.w * 4 + lane];
        uint4 u4 = g4[(size_t)e1.x * 4 + lane];
        uint4 u5 = g4[(size_t)e1.y * 4 + lane];
        uint4 u6 = g4[(size_t)e1.z * 4 + lane];
        uint4 u7 = g4[(size_t)e1.w * 4 + lane];
        acc8(u0, s); acc8(u1, s); acc8(u2, s); acc8(u3, s);
        acc8(u4, s); acc8(u5, s); acc8(u6, s); acc8(u7, s);
        j += 8;
    }
    if (j + 4 <= end) {
        int4 e0 = *(const int4*)(es + j);
        uint4 u0 = g4[(size_t)e0.x * 4 + lane];
        uint4 u1 = g4[(size_t)e0.y * 4 + lane];
        uint4 u2 = g4[(size_t)e0.z * 4 + lane];
        uint4 u3 = g4[(size_t)e0.w * 4 + lane];
        acc8(u0, s); acc8(u1, s); acc8(u2, s); acc8(u3, s);
        j += 4;
    }
    for (; j < end; ++j) acc8(g4[(size_t)es[j] * 4 + lane], s);
}

// ---- fused hidden layer: gout = fp16(dis (.) relu(agg(g) @ W + b)) ---------
// 64 nodes/block, 4 lanes/node. Agg result (fp32, pre-fp16-quant!) goes to
// LDS; 32x32 GEMM epilogue reads Xs/Ws broadcast, ONE barrier total.
__global__ __launch_bounds__(256)
void k_fused16(const int* __restrict__ starts, const int* __restrict__ es,
               const float* __restrict__ dis, const __half* __restrict__ g,
               const float* __restrict__ W, const float* __restrict__ bias,
               __half* __restrict__ gout, int n) {
    __shared__ float Ws[32][33];
    __shared__ float Xs[64][33];
    int t = threadIdx.x;
    for (int i = t; i < 1024; i += 256) Ws[i >> 5][i & 31] = W[i];
    int r = t >> 2, lane = t & 3;
    int node = blockIdx.x * 64 + r;
    bool alive = node < n;
    float dd = 0.f;
    if (alive) {
        float s[8] = {0, 0, 0, 0, 0, 0, 0, 0};
        gather32(starts, es, (const uint4*)g, node, lane, s);
        dd = dis[node];
#pragma unroll
        for (int i = 0; i < 8; ++i) Xs[r][lane * 8 + i] = dd * s[i];
    }
    __syncthreads();                       // covers Ws and Xs
    if (alive) {
        int c0 = lane * 8;
        float acc[8];
#pragma unroll
        for (int i = 0; i < 8; ++i) acc[i] = bias[c0 + i];
#pragma unroll 8
        for (int k = 0; k < 32; ++k) {
            float xv = Xs[r][k];
#pragma unroll
            for (int i = 0; i < 8; ++i) acc[i] += xv * Ws[k][c0 + i];
        }
        __half2 h0 = __floats2half2_rn(dd * fmaxf(acc[0], 0.f), dd * fmaxf(acc[1], 0.f));
        __half2 h1 = __floats2half2_rn(dd * fmaxf(acc[2], 0.f), dd * fmaxf(acc[3], 0.f));
        __half2 h2 = __floats2half2_rn(dd * fmaxf(acc[4], 0.f), dd * fmaxf(acc[5], 0.f));
        __half2 h3 = __floats2half2_rn(dd * fmaxf(acc[6], 0.f), dd * fmaxf(acc[7], 0.f));
        uint4 u;
        u.x = *(unsigned int*)&h0; u.y = *(unsigned int*)&h1;
        u.z = *(unsigned int*)&h2; u.w = *(unsigned int*)&h3;
        ((uint4*)gout)[(size_t)node * 4 + lane] = u;
    }
}

// ---- fused output layer: out = [agg(g) @ Wmu + bmu | agg(g) @ Wlv + blv] ---
__global__ __launch_bounds__(256)
void k_fused_final(const int* __restrict__ starts, const int* __restrict__ es,
                   const float* __restrict__ dis, const __half* __restrict__ g,
                   const float* __restrict__ Wmu, const float* __restrict__ Wlv,
                   const float* __restrict__ bmu, const float* __restrict__ blv,
                   float* __restrict__ out, int n) {
    __shared__ float Ws[32][66];           // [k][c], mu cols 0-31, lv cols 32-63
    __shared__ float Xs[64][33];
    int t = threadIdx.x;
    for (int i = t; i < 1024; i += 256) {
        Ws[i >> 5][i & 31]        = Wmu[i];
        Ws[i >> 5][32 + (i & 31)] = Wlv[i];
    }
    int r = t >> 2, lane = t & 3;
    int node = blockIdx.x * 64 + r;
    bool alive = node < n;
    if (alive) {
        float s[8] = {0, 0, 0, 0, 0, 0, 0, 0};
        gather32(starts, es, (const uint4*)g, node, lane, s);
        float dd = dis[node];
#pragma unroll
        for (int i = 0; i < 8; ++i) Xs[r][lane * 8 + i] = dd * s[i];
    }
    __syncthreads();
    if (alive) {
        int c0 = lane * 8;
        float am[8], al[8];
#pragma unroll
        for (int i = 0; i < 8; ++i) { am[i] = bmu[c0 + i]; al[i] = blv[c0 + i]; }
#pragma unroll 4
        for (int k = 0; k < 32; ++k) {
            float xv = Xs[r][k];
#pragma unroll
            for (int i = 0; i < 8; ++i) {
                am[i] += xv * Ws[k][c0 + i];
                al[i] += xv * Ws[k][32 + c0 + i];
            }
        }
        float4* om = (float4*)out + (size_t)node * 8 + lane * 2;
        om[0] = make_float4(am[0], am[1], am[2], am[3]);
        om[1] = make_float4(am[4], am[5], am[6], am[7]);
        float4* ol = (float4*)(out + (size_t)n * 32) + (size_t)node * 8 + lane * 2;
        ol[0] = make_float4(al[0], al[1], al[2], al[3]);
        ol[1] = make_float4(al[4], al[5], al[6], al[7]);
    }
}

// ---- launch ----------------------------------------------------------------

extern "C" void kernel_launch(void* const* d_in, const int* in_sizes, int n_in,
                              void* d_out, int out_size, void* d_ws, size_t ws_size,
                              hipStream_t stream) {
    const float* x   = (const float*)d_in[0];
    const int*   ei  = (const int*)d_in[1];
    const float* W1  = (const float*)d_in[2];
    const float* b1  = (const float*)d_in[3];
    const float* W2  = (const float*)d_in[4];
    const float* b2  = (const float*)d_in[5];
    const float* Wmu = (const float*)d_in[6];
    const float* bmu = (const float*)d_in[7];
    const float* Wlv = (const float*)d_in[8];
    const float* blv = (const float*)d_in[9];
    float* out = (float*)d_out;

    int n = in_sizes[0] / 32;   // 100000
    int E = in_sizes[1] / 2;    // 1600000
    const int* src = ei;
    const int* dst = ei + E;
    int nbuck = (n + BK - 1) >> BK_BITS;   // 196 (<= 256)

    // workspace layout (all segments 16B-aligned)
    int*    bcur   = (int*)d_ws;                      // 256
    int     npad   = (n + 4) & ~3;
    int*    starts = bcur + 256;                      // n+1 (padded)
    float*  dis    = (float*)(starts + npad);         // n
    int*    es     = (int*)(dis + n);                 // E
    __half* gA     = (__half*)(es + E);               // n*32 fp16
    __half* gB     = gA + (size_t)n * 32;             // n*32 fp16
    int*    ebuf   = (int*)(gB + (size_t)n * 32);     // 256*CAP ints (16.8 MB)

    int nblk  = (E + CHUNK - 1) / CHUNK;
    int agrid = (n + 63) / 64;

    // ---- edge preprocessing ----
    hipMemsetAsync(bcur, 0, 256 * sizeof(int), stream);
    k_bucket<<<nblk, 256, 0, stream>>>(src, dst, bcur, ebuf, E);
    k_finalize<<<nbuck, BK, 0, stream>>>(bcur, starts, dis, ebuf, es, x, gA, n, E);

    // ---- layer 1 (agg + gemm fused) ----
    k_fused16<<<agrid, 256, 0, stream>>>(starts, es, dis, gA, W1, b1, gB, n);
    // ---- layer 2 ----
    k_fused16<<<agrid, 256, 0, stream>>>(starts, es, dis, gB, W2, b2, gA, n);
    // ---- mu/logvar ----
    k_fused_final<<<agrid, 256, 0, stream>>>(starts, es, dis, gA, Wmu, Wlv, bmu, blv, out, n);
}